// Round 6
// baseline (452.382 us; speedup 1.0000x reference)
//
#include <hip/hip_runtime.h>

// bf16 stored as raw ushort everywhere; MFMA consumes __bf16 vectors.
typedef unsigned short u16;
using bf16x8  = __attribute__((ext_vector_type(8))) __bf16;
using floatx4 = __attribute__((ext_vector_type(4))) float;

__device__ __forceinline__ u16 f2bf(float f) {
  unsigned int u = __builtin_bit_cast(unsigned int, f);
  u += 0x7fffu + ((u >> 16) & 1u);          // round-to-nearest-even
  return (u16)(u >> 16);
}

#define AS1(p) ((const __attribute__((address_space(1))) void*)(p))
#define AS3(p) ((__attribute__((address_space(3))) void*)(p))

// ---- GEMM core: verified m97 structure, BK=32 ONLY. R5 measured BK=64 as a
// regression on this structure (gemm_qkv 87->97us, VALUBusy 15->29%): doubled
// per-barrier staging adds VALU + longer vmcnt(0) drain. Do not re-widen. ----
#define GEMM_PROLOGUE()                                                      \
  __shared__ u16 As[128 * 32];                                               \
  __shared__ u16 Bs[128 * 32];                                               \
  const int tid  = threadIdx.x;                                              \
  const int wave = tid >> 6, lane = tid & 63;                                \
  const int wm = (wave >> 1) * 64, wn = (wave & 1) * 64;                     \
  const long bm = (long)blockIdx.y * 128, bn = (long)blockIdx.x * 128;       \
  floatx4 acc[4][4] = {};                                                    \
  const int srow = lane >> 2;                                                \
  const int scol = (lane & 3) * 8;                                           \
  const int c0 = wave * 2, c1 = c0 + 1;                                      \
  const int fr = lane & 15;                                                  \
  const int kq = (lane >> 4) * 8;

#define GEMM_KSTEP(Ab, Bb, K, k0)                                            \
  {                                                                          \
    __syncthreads();                                                         \
    __builtin_amdgcn_global_load_lds(AS1(Ab + (long)(c0*16 + srow)*K + k0 + scol), AS3(As + c0*512), 16, 0, 0); \
    __builtin_amdgcn_global_load_lds(AS1(Ab + (long)(c1*16 + srow)*K + k0 + scol), AS3(As + c1*512), 16, 0, 0); \
    __builtin_amdgcn_global_load_lds(AS1(Bb + (long)(c0*16 + srow)*K + k0 + scol), AS3(Bs + c0*512), 16, 0, 0); \
    __builtin_amdgcn_global_load_lds(AS1(Bb + (long)(c1*16 + srow)*K + k0 + scol), AS3(Bs + c1*512), 16, 0, 0); \
    __syncthreads();                                                         \
    bf16x8 af[4], bfv[4];                                                    \
    _Pragma("unroll")                                                        \
    for (int mi = 0; mi < 4; ++mi)                                           \
      af[mi] = *(const bf16x8*)(As + (wm + mi*16 + fr)*32 + kq);             \
    _Pragma("unroll")                                                        \
    for (int ni = 0; ni < 4; ++ni)                                           \
      bfv[ni] = *(const bf16x8*)(Bs + (wn + ni*16 + fr)*32 + kq);            \
    _Pragma("unroll")                                                        \
    for (int mi = 0; mi < 4; ++mi)                                           \
      _Pragma("unroll")                                                      \
      for (int ni = 0; ni < 4; ++ni)                                         \
        acc[mi][ni] = __builtin_amdgcn_mfma_f32_16x16x32_bf16(af[mi], bfv[ni], acc[mi][ni], 0, 0, 0); \
  }

// C = A * Bt^T (+bias); out_mode: 0 = fp32 row-major; 1 = bf16 row-major.
__global__ __launch_bounds__(256) void gemm_bt(
    const u16* __restrict__ A, const u16* __restrict__ Bt,
    void* __restrict__ Cout, const float* __restrict__ bias,
    int N, int K, float alpha, int out_mode)
{
  GEMM_PROLOGUE();
  const u16* Ab = A + bm * K;
  const u16* Bb = Bt + bn * K;
  for (int k0 = 0; k0 < K; k0 += 32) GEMM_KSTEP(Ab, Bb, K, k0);

  // C/D layout: col = lane&15, row = (lane>>4)*4 + r   (m89-verified)
  const int orow = (lane >> 4) * 4;
  const int ocol = lane & 15;
#pragma unroll
  for (int ni = 0; ni < 4; ++ni) {
    long col = bn + wn + ni*16 + ocol;
    float bv = bias ? bias[col] : 0.0f;
#pragma unroll
    for (int mi = 0; mi < 4; ++mi) {
      long row = bm + wm + mi*16 + orow;
      if (out_mode == 0) {
        float* C = (float*)Cout;
#pragma unroll
        for (int r = 0; r < 4; ++r)
          C[(row + r) * N + col] = acc[mi][ni][r] * alpha + bv;
      } else {
        u16* C = (u16*)Cout;
#pragma unroll
        for (int r = 0; r < 4; ++r)
          C[(row + r) * N + col] = f2bf(acc[mi][ni][r] * alpha + bv);
      }
    }
  }
}

// Batch-combined QK^T + unnormalized exp. blockIdx.z = batch.
// P[z] = exp(scale * q_z k_z^T) bf16 [4096][4096]; per-row partial sums
// lpart[z][cg][4096] fp32, cg = blockIdx.x*2 + wn/64.
// No max-subtraction: |scores| <= ~20 << 88 (fp32 exp range).
__global__ __launch_bounds__(256) void gemm_qk_exp(
    const u16* __restrict__ q, const u16* __restrict__ k,
    u16* __restrict__ probs, float* __restrict__ lpart, float alpha)
{
  const int N = 4096, K = 1024;
  const long z = blockIdx.z;
  const u16* A  = q + z * 4096 * 1024;
  const u16* Bt = k + z * 4096 * 1024;
  u16* P = probs + z * 4096L * 4096;
  float* lp = lpart + z * 64 * 4096;

  GEMM_PROLOGUE();
  const u16* Ab = A + bm * K;
  const u16* Bb = Bt + bn * K;
  for (int k0 = 0; k0 < K; k0 += 32) GEMM_KSTEP(Ab, Bb, K, k0);

  const int orow = (lane >> 4) * 4;
  const int ocol = lane & 15;
  float rowsum[4][4];
#pragma unroll
  for (int mi = 0; mi < 4; ++mi)
#pragma unroll
    for (int r = 0; r < 4; ++r) rowsum[mi][r] = 0.0f;

#pragma unroll
  for (int ni = 0; ni < 4; ++ni) {
    long col = bn + wn + ni*16 + ocol;
#pragma unroll
    for (int mi = 0; mi < 4; ++mi) {
      long row = bm + wm + mi*16 + orow;
#pragma unroll
      for (int r = 0; r < 4; ++r) {
        float p = __expf(acc[mi][ni][r] * alpha);
        P[(row + r) * N + col] = f2bf(p);
        rowsum[mi][r] += p;
      }
    }
  }
  // reduce rowsum across the 16 lanes of each quad (row lives in one quad)
#pragma unroll
  for (int mi = 0; mi < 4; ++mi)
#pragma unroll
    for (int r = 0; r < 4; ++r) {
      float s = rowsum[mi][r];
      s += __shfl_xor(s, 1); s += __shfl_xor(s, 2);
      s += __shfl_xor(s, 4); s += __shfl_xor(s, 8);
      rowsum[mi][r] = s;
    }
  if (ocol == 0) {
    long cg = blockIdx.x * 2 + (wn >> 6);
#pragma unroll
    for (int mi = 0; mi < 4; ++mi)
#pragma unroll
      for (int r = 0; r < 4; ++r)
        lp[cg * 4096 + bm + wm + mi*16 + orow + r] = rowsum[mi][r];
  }
}

// Fused QKV projection: A=xb [8192,1024], Bt=WqkvT [3072,1024], grid (24,64).
// cols [0,1024)->qb; [1024,2048)->kb; [2048,3072)->vT[b][d][s] transposed.
__global__ __launch_bounds__(256) void gemm_qkv(
    const u16* __restrict__ A, const u16* __restrict__ Bt,
    u16* __restrict__ qb, u16* __restrict__ kb, u16* __restrict__ vT,
    const float* __restrict__ bq, const float* __restrict__ bk,
    const float* __restrict__ bv)
{
  const int K = 1024;
  GEMM_PROLOGUE();
  const u16* Ab = A + bm * K;
  const u16* Bb = Bt + bn * K;
  for (int k0 = 0; k0 < K; k0 += 32) GEMM_KSTEP(Ab, Bb, K, k0);

  const int orow = (lane >> 4) * 4;
  const int ocol = lane & 15;
#pragma unroll
  for (int ni = 0; ni < 4; ++ni) {
    long col = bn + wn + ni*16 + ocol;   // [0,3072)
    const float* bias = (col < 1024) ? bq : (col < 2048) ? bk : bv;
    float bvv = bias[col & 1023];
#pragma unroll
    for (int mi = 0; mi < 4; ++mi) {
      long row = bm + wm + mi*16 + orow;   // [0,8192)
      if (col < 2048) {
        u16* C = (col < 1024) ? qb : kb;
        long cc = col & 1023;
#pragma unroll
        for (int r = 0; r < 4; ++r)
          C[(row + r) * 1024 + cc] = f2bf(acc[mi][ni][r] + bvv);
      } else {
        long b_ = row >> 12, s = row & 4095, d = col - 2048;
        ushort4 o;
        o.x = f2bf(acc[mi][ni][0] + bvv);
        o.y = f2bf(acc[mi][ni][1] + bvv);
        o.z = f2bf(acc[mi][ni][2] + bvv);
        o.w = f2bf(acc[mi][ni][3] + bvv);
        *(ushort4*)(vT + b_ * (1024L * 4096) + d * 4096L + s) = o;
      }
    }
  }
}

// Batch-combined PV split-K=2: blockIdx.z = batch*2 + split.
// A = probs[b] [4096,4096] bf16, Bt = vT[b] [1024,4096] bf16.
// fp32 partials: batch b -> region pA (b=0) / pB (b=1), slice `split`
// ([4096][1024] fp32 each).  Grid (8,32,4) = 1024 blocks = 4/CU.
__global__ __launch_bounds__(256) void gemm_pv_splitk(
    const u16* __restrict__ probs, const u16* __restrict__ vT,
    float* __restrict__ pA, float* __restrict__ pB)
{
  const int N = 1024, K = 4096, Ks = 2048;
  const long z = blockIdx.z, b = z >> 1, sp = z & 1;
  const u16* A  = probs + b * 4096L * 4096;
  const u16* Bt = vT + b * 1024L * 4096;
  float* part = (b ? pB : pA) + sp * 4096L * 1024;

  GEMM_PROLOGUE();
  const u16* Ab = A + bm * K;
  const u16* Bb = Bt + bn * K;
  const int kbeg = (int)sp * Ks, kend = kbeg + Ks;
  for (int k0 = kbeg; k0 < kend; k0 += 32) GEMM_KSTEP(Ab, Bb, K, k0);

  const int orow = (lane >> 4) * 4;
  const int ocol = lane & 15;
#pragma unroll
  for (int ni = 0; ni < 4; ++ni) {
    long col = bn + wn + ni*16 + ocol;
#pragma unroll
    for (int mi = 0; mi < 4; ++mi) {
      long row = bm + wm + mi*16 + orow;
#pragma unroll
      for (int r = 0; r < 4; ++r)
        part[(row + r) * N + col] = acc[mi][ni][r];
    }
  }
}

// Combined reduce + softmax-normalize: grid (4096 rows, 2 batches).
// Wave 0 sums the 64 lpart entries for this row (denominator), broadcast;
// out[b][row] = (slice0 + slice1) / l as bf16.
__global__ __launch_bounds__(256) void reduce2_div_row(
    const float* __restrict__ pA, const float* __restrict__ pB,
    const float* __restrict__ lpart, u16* __restrict__ ob)
{
  const int row = blockIdx.x;           // [0,4096)
  const long b = blockIdx.y;
  const int tid = threadIdx.x;
  const float* part = b ? pB : pA;
  const float* lp = lpart + b * 64 * 4096;
  __shared__ float sl;
  if (tid < 64) {
    float s = lp[(long)tid * 4096 + row];
#pragma unroll
    for (int off = 32; off; off >>= 1) s += __shfl_down(s, off);
    if (tid == 0) sl = s;
  }
  __syncthreads();
  const float inv = 1.0f / sl;
  const long base = (long)row * 1024 + tid * 4;
  float4 a  = *(const float4*)(part + base);
  float4 b2 = *(const float4*)(part + 4096L * 1024 + base);
  ushort4 o;
  o.x = f2bf((a.x + b2.x) * inv);
  o.y = f2bf((a.y + b2.y) * inv);
  o.z = f2bf((a.z + b2.z) * inv);
  o.w = f2bf((a.w + b2.w) * inv);
  *(ushort4*)(ob + b * 4096L * 1024 + base) = o;
}

__global__ __launch_bounds__(256) void cast_f32_to_bf16(
    const float* __restrict__ in, u16* __restrict__ out, int n4)
{
  int i = blockIdx.x * 256 + threadIdx.x;
  if (i >= n4) return;
  float4 f = ((const float4*)in)[i];
  ushort4 o;
  o.x = f2bf(f.x); o.y = f2bf(f.y); o.z = f2bf(f.z); o.w = f2bf(f.w);
  ((ushort4*)out)[i] = o;
}

// z in [0,4): out_z[c][r] = (bf16)in_z[r][c], 1024x1024 each
__global__ void transpose_w4(
    const float* __restrict__ W0, const float* __restrict__ W1,
    const float* __restrict__ W2, const float* __restrict__ W3,
    u16* __restrict__ O0, u16* __restrict__ O1,
    u16* __restrict__ O2, u16* __restrict__ O3)
{
  __shared__ float tile[32][33];
  const int z = blockIdx.z;
  const float* in = (z == 0) ? W0 : (z == 1) ? W1 : (z == 2) ? W2 : W3;
  u16* out = (z == 0) ? O0 : (z == 1) ? O1 : (z == 2) ? O2 : O3;
  int bx = blockIdx.x * 32, by = blockIdx.y * 32;
  int tx = threadIdx.x, ty = threadIdx.y;
  for (int i = ty; i < 32; i += 8)
    tile[i][tx] = in[(long)(by + i) * 1024 + bx + tx];
  __syncthreads();
  for (int i = ty; i < 32; i += 8)
    out[(long)(bx + i) * 1024 + by + tx] = f2bf(tile[tx][i]);
}

extern "C" void kernel_launch(void* const* d_in, const int* in_sizes, int n_in,
                              void* d_out, int out_size, void* d_ws, size_t ws_size,
                              hipStream_t stream) {
  const float* x  = (const float*)d_in[0];
  const float* Wq = (const float*)d_in[1];
  const float* bq = (const float*)d_in[2];
  const float* Wk = (const float*)d_in[3];
  const float* bk = (const float*)d_in[4];
  const float* Wv = (const float*)d_in[5];
  const float* bv = (const float*)d_in[6];
  const float* Wo = (const float*)d_in[7];
  const float* bo = (const float*)d_in[8];
  float* out = (float*)d_out;

  const int B = 2, S = 4096, D = 1024;
  const long MS = (long)B * S;  // 8192
  const long MB = 1L << 20;

  // ---- workspace layout (top usage 168 MiB; ws_size >= 168 MiB proven) ----
  //  [0,16M)    qb  bf16 [8192,1024]   -- dead after QK_exp; reused as
  //  [16,32M)   kb  bf16 [8192,1024]   -- PV partials region A (32M fp32)
  //  [32,48M)   vT  bf16 [B][1024][4096]
  //  [48,64M)   xb  bf16 [8192,1024]   -- aliased with ob (xb dead before PV)
  //  [64,72M)   WqkvT bf16 [3072,1024] + WoT bf16 [1024,1024]
  //  [72,136M)  probs bf16 [B][4096][4096]  (both batches)
  //  [136,168M) PV partials region B (batch 1): [2][4096][1024] fp32
  // d_out (32MB fp32, dead until final proj) hosts lpart [B][64][4096] fp32.
  char* w = (char*)d_ws;
  u16* qb  = (u16*)(w);
  u16* kb  = (u16*)(w + 16 * MB);
  u16* vT  = (u16*)(w + 32 * MB);
  u16* xb  = (u16*)(w + 48 * MB);
  u16* ob  = xb;                        // alias: xb dead before ob written
  u16* WqkvT = (u16*)(w + 64 * MB);
  u16* WoT = WqkvT + 3072L * 1024;
  u16* probs = (u16*)(w + 72 * MB);
  float* partA = (float*)(w);           // over qb+kb, dead after QK_exp
  float* partB = (float*)(w + 136 * MB);
  float* lpart = (float*)d_out;         // [2][64][4096] fp32 = 2MB

  // 1. cast x -> bf16
  cast_f32_to_bf16<<<dim3((unsigned)(MS * D / 4 / 256)), dim3(256), 0, stream>>>(
      x, xb, (int)(MS * D / 4));

  // 2. transpose+cast all 4 weights in one launch
  transpose_w4<<<dim3(32, 32, 4), dim3(32, 8), 0, stream>>>(
      Wq, Wk, Wv, Wo, WqkvT, WqkvT + 1024L * 1024, WqkvT + 2048L * 1024, WoT);

  // 3. fused QKV projection: grid (24,64) = 1536 blocks
  gemm_qkv<<<dim3(3 * D / 128, MS / 128), 256, 0, stream>>>(
      xb, WqkvT, qb, kb, vT, bq, bk, bv);

  // 4. attention, both batches per launch
  const float scale = 0.125f;  // 1/sqrt(64)
  gemm_qk_exp<<<dim3(S / 128, S / 128, B), 256, 0, stream>>>(
      qb, kb, probs, lpart, scale);
  // qb/kb now dead -> partA overlays them
  gemm_pv_splitk<<<dim3(D / 128, S / 128, 2 * B), 256, 0, stream>>>(
      probs, vT, partA, partB);
  reduce2_div_row<<<dim3(S, B), 256, 0, stream>>>(partA, partB, lpart, ob);

  // 5. final projection -> fp32 d_out (overwrites lpart scratch)
  gemm_bt<<<dim3(D / 128, MS / 128), 256, 0, stream>>>(ob, WoT, out, bo, D, D, 1.0f, 0);
}

// Round 7
// 451.025 us; speedup vs baseline: 1.0030x; 1.0030x over previous
//
#include <hip/hip_runtime.h>

// bf16 stored as raw ushort everywhere; MFMA consumes __bf16 vectors.
typedef unsigned short u16;
using bf16x8  = __attribute__((ext_vector_type(8))) __bf16;
using floatx4 = __attribute__((ext_vector_type(4))) float;

__device__ __forceinline__ u16 f2bf(float f) {
  unsigned int u = __builtin_bit_cast(unsigned int, f);
  u += 0x7fffu + ((u >> 16) & 1u);          // round-to-nearest-even
  return (u16)(u >> 16);
}

#define AS1(p) ((const __attribute__((address_space(1))) void*)(p))
#define AS3(p) ((__attribute__((address_space(3))) void*)(p))

// ---- GEMM core: verified m97 structure, BK=32 ONLY. R5 measured BK=64 as a
// regression (gemm_qkv 87->97us, VALUBusy 15->29%). Do not re-widen. ----
// GEMM_PROLOGUE_AT takes explicit tile origins so callers can swizzle the
// block->tile mapping (XCD locality) without touching the core.
#define GEMM_PROLOGUE_AT(bmv, bnv)                                           \
  __shared__ u16 As[128 * 32];                                               \
  __shared__ u16 Bs[128 * 32];                                               \
  const int tid  = threadIdx.x;                                              \
  const int wave = tid >> 6, lane = tid & 63;                                \
  const int wm = (wave >> 1) * 64, wn = (wave & 1) * 64;                     \
  const long bm = (bmv), bn = (bnv);                                         \
  floatx4 acc[4][4] = {};                                                    \
  const int srow = lane >> 2;                                                \
  const int scol = (lane & 3) * 8;                                           \
  const int c0 = wave * 2, c1 = c0 + 1;                                      \
  const int fr = lane & 15;                                                  \
  const int kq = (lane >> 4) * 8;

#define GEMM_PROLOGUE() GEMM_PROLOGUE_AT((long)blockIdx.y * 128, (long)blockIdx.x * 128)

#define GEMM_KSTEP(Ab, Bb, K, k0)                                            \
  {                                                                          \
    __syncthreads();                                                         \
    __builtin_amdgcn_global_load_lds(AS1(Ab + (long)(c0*16 + srow)*K + k0 + scol), AS3(As + c0*512), 16, 0, 0); \
    __builtin_amdgcn_global_load_lds(AS1(Ab + (long)(c1*16 + srow)*K + k0 + scol), AS3(As + c1*512), 16, 0, 0); \
    __builtin_amdgcn_global_load_lds(AS1(Bb + (long)(c0*16 + srow)*K + k0 + scol), AS3(Bs + c0*512), 16, 0, 0); \
    __builtin_amdgcn_global_load_lds(AS1(Bb + (long)(c1*16 + srow)*K + k0 + scol), AS3(Bs + c1*512), 16, 0, 0); \
    __syncthreads();                                                         \
    bf16x8 af[4], bfv[4];                                                    \
    _Pragma("unroll")                                                        \
    for (int mi = 0; mi < 4; ++mi)                                           \
      af[mi] = *(const bf16x8*)(As + (wm + mi*16 + fr)*32 + kq);             \
    _Pragma("unroll")                                                        \
    for (int ni = 0; ni < 4; ++ni)                                           \
      bfv[ni] = *(const bf16x8*)(Bs + (wn + ni*16 + fr)*32 + kq);            \
    _Pragma("unroll")                                                        \
    for (int mi = 0; mi < 4; ++mi)                                           \
      _Pragma("unroll")                                                      \
      for (int ni = 0; ni < 4; ++ni)                                         \
        acc[mi][ni] = __builtin_amdgcn_mfma_f32_16x16x32_bf16(af[mi], bfv[ni], acc[mi][ni], 0, 0, 0); \
  }

// C = A * Bt^T (+bias); out_mode: 0 = fp32 row-major; 1 = bf16 row-major.
__global__ __launch_bounds__(256) void gemm_bt(
    const u16* __restrict__ A, const u16* __restrict__ Bt,
    void* __restrict__ Cout, const float* __restrict__ bias,
    int N, int K, float alpha, int out_mode)
{
  GEMM_PROLOGUE();
  const u16* Ab = A + bm * K;
  const u16* Bb = Bt + bn * K;
  for (int k0 = 0; k0 < K; k0 += 32) GEMM_KSTEP(Ab, Bb, K, k0);

  // C/D layout: col = lane&15, row = (lane>>4)*4 + r   (m89-verified)
  const int orow = (lane >> 4) * 4;
  const int ocol = lane & 15;
#pragma unroll
  for (int ni = 0; ni < 4; ++ni) {
    long col = bn + wn + ni*16 + ocol;
    float bv = bias ? bias[col] : 0.0f;
#pragma unroll
    for (int mi = 0; mi < 4; ++mi) {
      long row = bm + wm + mi*16 + orow;
      if (out_mode == 0) {
        float* C = (float*)Cout;
#pragma unroll
        for (int r = 0; r < 4; ++r)
          C[(row + r) * N + col] = acc[mi][ni][r] * alpha + bv;
      } else {
        u16* C = (u16*)Cout;
#pragma unroll
        for (int r = 0; r < 4; ++r)
          C[(row + r) * N + col] = f2bf(acc[mi][ni][r] * alpha + bv);
      }
    }
  }
}

// Batch-combined QK^T + unnormalized exp, XCD-swizzled.
// Grid (32,32,2) = 2048 blocks. lin%8 = XCD (assumed round-robin):
// batch = xcd>>2; each XCD owns an 8-row by-band of one batch and sweeps bx
// in 8-wide tiles -> resident window ~4MB (fits 4MB per-XCD L2); q fetched
// once, k 4x. P[b] = exp(scale*q k^T) bf16; lpart[b][cg][4096] partial sums.
__global__ __launch_bounds__(256) void gemm_qk_exp(
    const u16* __restrict__ q, const u16* __restrict__ k,
    u16* __restrict__ probs, float* __restrict__ lpart, float alpha)
{
  const int N = 4096, K = 1024;
  const int lin = blockIdx.x + (blockIdx.y << 5) + (blockIdx.z << 10);
  const int xcd = lin & 7, j = lin >> 3;          // j in [0,256)
  const long b = xcd >> 2;
  const int band = (xcd & 3) * 8;                 // by-band base
  const int t = j >> 6, w = j & 63;               // 4 bx-tiles of 64 blocks
  const int bx = t * 8 + (w & 7);                 // [0,32)
  const int by = band + (w >> 3);                 // [0,32)

  const u16* A  = q + b * 4096 * 1024;
  const u16* Bt = k + b * 4096 * 1024;
  u16* P = probs + b * 4096L * 4096;
  float* lp = lpart + b * 64 * 4096;

  GEMM_PROLOGUE_AT((long)by * 128, (long)bx * 128);
  const u16* Ab = A + bm * K;
  const u16* Bb = Bt + bn * K;
  for (int k0 = 0; k0 < K; k0 += 32) GEMM_KSTEP(Ab, Bb, K, k0);

  const int orow = (lane >> 4) * 4;
  const int ocol = lane & 15;
  float rowsum[4][4];
#pragma unroll
  for (int mi = 0; mi < 4; ++mi)
#pragma unroll
    for (int r = 0; r < 4; ++r) rowsum[mi][r] = 0.0f;

#pragma unroll
  for (int ni = 0; ni < 4; ++ni) {
    long col = bn + wn + ni*16 + ocol;
#pragma unroll
    for (int mi = 0; mi < 4; ++mi) {
      long row = bm + wm + mi*16 + orow;
#pragma unroll
      for (int r = 0; r < 4; ++r) {
        float p = __expf(acc[mi][ni][r] * alpha);
        P[(row + r) * N + col] = f2bf(p);
        rowsum[mi][r] += p;
      }
    }
  }
  // reduce rowsum across the 16 lanes of each quad (row lives in one quad)
#pragma unroll
  for (int mi = 0; mi < 4; ++mi)
#pragma unroll
    for (int r = 0; r < 4; ++r) {
      float s = rowsum[mi][r];
      s += __shfl_xor(s, 1); s += __shfl_xor(s, 2);
      s += __shfl_xor(s, 4); s += __shfl_xor(s, 8);
      rowsum[mi][r] = s;
    }
  if (ocol == 0) {
    long cg = bx * 2 + (wn >> 6);
#pragma unroll
    for (int mi = 0; mi < 4; ++mi)
#pragma unroll
      for (int r = 0; r < 4; ++r)
        lp[cg * 4096 + bm + wm + mi*16 + orow + r] = rowsum[mi][r];
  }
}

// Fused QKV projection: A=xb [8192,1024], Bt=WqkvT [3072,1024], grid (24,64).
// cols [0,1024)->qb; [1024,2048)->kb; [2048,3072)->vT[b][d][s] transposed.
__global__ __launch_bounds__(256) void gemm_qkv(
    const u16* __restrict__ A, const u16* __restrict__ Bt,
    u16* __restrict__ qb, u16* __restrict__ kb, u16* __restrict__ vT,
    const float* __restrict__ bq, const float* __restrict__ bk,
    const float* __restrict__ bv)
{
  const int K = 1024;
  GEMM_PROLOGUE();
  const u16* Ab = A + bm * K;
  const u16* Bb = Bt + bn * K;
  for (int k0 = 0; k0 < K; k0 += 32) GEMM_KSTEP(Ab, Bb, K, k0);

  const int orow = (lane >> 4) * 4;
  const int ocol = lane & 15;
#pragma unroll
  for (int ni = 0; ni < 4; ++ni) {
    long col = bn + wn + ni*16 + ocol;   // [0,3072)
    const float* bias = (col < 1024) ? bq : (col < 2048) ? bk : bv;
    float bvv = bias[col & 1023];
#pragma unroll
    for (int mi = 0; mi < 4; ++mi) {
      long row = bm + wm + mi*16 + orow;   // [0,8192)
      if (col < 2048) {
        u16* C = (col < 1024) ? qb : kb;
        long cc = col & 1023;
#pragma unroll
        for (int r = 0; r < 4; ++r)
          C[(row + r) * 1024 + cc] = f2bf(acc[mi][ni][r] + bvv);
      } else {
        long b_ = row >> 12, s = row & 4095, d = col - 2048;
        ushort4 o;
        o.x = f2bf(acc[mi][ni][0] + bvv);
        o.y = f2bf(acc[mi][ni][1] + bvv);
        o.z = f2bf(acc[mi][ni][2] + bvv);
        o.w = f2bf(acc[mi][ni][3] + bvv);
        *(ushort4*)(vT + b_ * (1024L * 4096) + d * 4096L + s) = o;
      }
    }
  }
}

// Batch-combined PV split-K=2, XCD-swizzled. Grid (8,32,4) = 1024 blocks.
// lin%8 = XCD: each (batch,split) K-slice is owned by one XCD *pair*
// (slice = xcd>>1), odd/even by-stripes alternate within the pair -> each
// probs A-stripe is fetched by exactly ONE XCD (R6 counter showed 8x
// refetch = 277MB without this).
__global__ __launch_bounds__(256) void gemm_pv_splitk(
    const u16* __restrict__ probs, const u16* __restrict__ vT,
    float* __restrict__ pA, float* __restrict__ pB)
{
  const int N = 1024, K = 4096, Ks = 2048;
  const int lin = blockIdx.x + (blockIdx.y << 3) + (blockIdx.z << 8);
  const int xcd = lin & 7, j = lin >> 3;          // j in [0,128)
  const int slice = xcd >> 1, half = xcd & 1;
  const long b = slice >> 1;
  const int sp = slice & 1;
  const int bx = j & 7;                           // [0,8)
  const int by = (j >> 3) * 2 + half;             // [0,32)

  const u16* A  = probs + b * 4096L * 4096;
  const u16* Bt = vT + b * 1024L * 4096;
  float* part = (b ? pB : pA) + sp * 4096L * 1024;

  GEMM_PROLOGUE_AT((long)by * 128, (long)bx * 128);
  const u16* Ab = A + bm * K;
  const u16* Bb = Bt + bn * K;
  const int kbeg = sp * Ks, kend = kbeg + Ks;
  for (int k0 = kbeg; k0 < kend; k0 += 32) GEMM_KSTEP(Ab, Bb, K, k0);

  const int orow = (lane >> 4) * 4;
  const int ocol = lane & 15;
#pragma unroll
  for (int ni = 0; ni < 4; ++ni) {
    long col = bn + wn + ni*16 + ocol;
#pragma unroll
    for (int mi = 0; mi < 4; ++mi) {
      long row = bm + wm + mi*16 + orow;
#pragma unroll
      for (int r = 0; r < 4; ++r)
        part[(row + r) * N + col] = acc[mi][ni][r];
    }
  }
}

// Combined reduce + softmax-normalize: grid (4096 rows, 2 batches).
// Wave 0 sums the 64 lpart entries for this row (denominator), broadcast;
// out[b][row] = (slice0 + slice1) / l as bf16.
__global__ __launch_bounds__(256) void reduce2_div_row(
    const float* __restrict__ pA, const float* __restrict__ pB,
    const float* __restrict__ lpart, u16* __restrict__ ob)
{
  const int row = blockIdx.x;           // [0,4096)
  const long b = blockIdx.y;
  const int tid = threadIdx.x;
  const float* part = b ? pB : pA;
  const float* lp = lpart + b * 64 * 4096;
  __shared__ float sl;
  if (tid < 64) {
    float s = lp[(long)tid * 4096 + row];
#pragma unroll
    for (int off = 32; off; off >>= 1) s += __shfl_down(s, off);
    if (tid == 0) sl = s;
  }
  __syncthreads();
  const float inv = 1.0f / sl;
  const long base = (long)row * 1024 + tid * 4;
  float4 a  = *(const float4*)(part + base);
  float4 b2 = *(const float4*)(part + 4096L * 1024 + base);
  ushort4 o;
  o.x = f2bf((a.x + b2.x) * inv);
  o.y = f2bf((a.y + b2.y) * inv);
  o.z = f2bf((a.z + b2.z) * inv);
  o.w = f2bf((a.w + b2.w) * inv);
  *(ushort4*)(ob + b * 4096L * 1024 + base) = o;
}

__global__ __launch_bounds__(256) void cast_f32_to_bf16(
    const float* __restrict__ in, u16* __restrict__ out, int n4)
{
  int i = blockIdx.x * 256 + threadIdx.x;
  if (i >= n4) return;
  float4 f = ((const float4*)in)[i];
  ushort4 o;
  o.x = f2bf(f.x); o.y = f2bf(f.y); o.z = f2bf(f.z); o.w = f2bf(f.w);
  ((ushort4*)out)[i] = o;
}

// z in [0,4): out_z[c][r] = (bf16)in_z[r][c], 1024x1024 each
__global__ void transpose_w4(
    const float* __restrict__ W0, const float* __restrict__ W1,
    const float* __restrict__ W2, const float* __restrict__ W3,
    u16* __restrict__ O0, u16* __restrict__ O1,
    u16* __restrict__ O2, u16* __restrict__ O3)
{
  __shared__ float tile[32][33];
  const int z = blockIdx.z;
  const float* in = (z == 0) ? W0 : (z == 1) ? W1 : (z == 2) ? W2 : W3;
  u16* out = (z == 0) ? O0 : (z == 1) ? O1 : (z == 2) ? O2 : O3;
  int bx = blockIdx.x * 32, by = blockIdx.y * 32;
  int tx = threadIdx.x, ty = threadIdx.y;
  for (int i = ty; i < 32; i += 8)
    tile[i][tx] = in[(long)(by + i) * 1024 + bx + tx];
  __syncthreads();
  for (int i = ty; i < 32; i += 8)
    out[(long)(bx + i) * 1024 + by + tx] = f2bf(tile[tx][i]);
}

extern "C" void kernel_launch(void* const* d_in, const int* in_sizes, int n_in,
                              void* d_out, int out_size, void* d_ws, size_t ws_size,
                              hipStream_t stream) {
  const float* x  = (const float*)d_in[0];
  const float* Wq = (const float*)d_in[1];
  const float* bq = (const float*)d_in[2];
  const float* Wk = (const float*)d_in[3];
  const float* bk = (const float*)d_in[4];
  const float* Wv = (const float*)d_in[5];
  const float* bv = (const float*)d_in[6];
  const float* Wo = (const float*)d_in[7];
  const float* bo = (const float*)d_in[8];
  float* out = (float*)d_out;

  const int B = 2, S = 4096, D = 1024;
  const long MS = (long)B * S;  // 8192
  const long MB = 1L << 20;

  // ---- workspace layout (top usage 168 MiB; ws_size >= 168 MiB proven) ----
  //  [0,16M)    qb  bf16 [8192,1024]   -- dead after QK_exp; reused as
  //  [16,32M)   kb  bf16 [8192,1024]   -- PV partials region A (32M fp32)
  //  [32,48M)   vT  bf16 [B][1024][4096]
  //  [48,64M)   xb  bf16 [8192,1024]   -- aliased with ob (xb dead before PV)
  //  [64,72M)   WqkvT bf16 [3072,1024] + WoT bf16 [1024,1024]
  //  [72,136M)  probs bf16 [B][4096][4096]  (both batches)
  //  [136,168M) PV partials region B (batch 1): [2][4096][1024] fp32
  // d_out (32MB fp32, dead until final proj) hosts lpart [B][64][4096] fp32.
  char* w = (char*)d_ws;
  u16* qb  = (u16*)(w);
  u16* kb  = (u16*)(w + 16 * MB);
  u16* vT  = (u16*)(w + 32 * MB);
  u16* xb  = (u16*)(w + 48 * MB);
  u16* ob  = xb;                        // alias: xb dead before ob written
  u16* WqkvT = (u16*)(w + 64 * MB);
  u16* WoT = WqkvT + 3072L * 1024;
  u16* probs = (u16*)(w + 72 * MB);
  float* partA = (float*)(w);           // over qb+kb, dead after QK_exp
  float* partB = (float*)(w + 136 * MB);
  float* lpart = (float*)d_out;         // [2][64][4096] fp32 = 2MB

  // 1. cast x -> bf16
  cast_f32_to_bf16<<<dim3((unsigned)(MS * D / 4 / 256)), dim3(256), 0, stream>>>(
      x, xb, (int)(MS * D / 4));

  // 2. transpose+cast all 4 weights in one launch
  transpose_w4<<<dim3(32, 32, 4), dim3(32, 8), 0, stream>>>(
      Wq, Wk, Wv, Wo, WqkvT, WqkvT + 1024L * 1024, WqkvT + 2048L * 1024, WoT);

  // 3. fused QKV projection: grid (24,64) = 1536 blocks
  gemm_qkv<<<dim3(3 * D / 128, MS / 128), 256, 0, stream>>>(
      xb, WqkvT, qb, kb, vT, bq, bk, bv);

  // 4. attention, both batches per launch (XCD-swizzled kernels)
  const float scale = 0.125f;  // 1/sqrt(64)
  gemm_qk_exp<<<dim3(S / 128, S / 128, B), 256, 0, stream>>>(
      qb, kb, probs, lpart, scale);
  // qb/kb now dead -> partA overlays them
  gemm_pv_splitk<<<dim3(D / 128, S / 128, 2 * B), 256, 0, stream>>>(
      probs, vT, partA, partB);
  reduce2_div_row<<<dim3(S, B), 256, 0, stream>>>(partA, partB, lpart, ob);

  // 5. final projection -> fp32 d_out (overwrites lpart scratch)
  gemm_bt<<<dim3(D / 128, MS / 128), 256, 0, stream>>>(ob, WoT, out, bo, D, D, 1.0f, 0);
}

// Round 8
// 427.132 us; speedup vs baseline: 1.0591x; 1.0559x over previous
//
#include <hip/hip_runtime.h>

// bf16 stored as raw ushort everywhere; MFMA consumes __bf16 vectors.
typedef unsigned short u16;
using bf16x8  = __attribute__((ext_vector_type(8))) __bf16;
using floatx4 = __attribute__((ext_vector_type(4))) float;

__device__ __forceinline__ u16 f2bf(float f) {
  unsigned int u = __builtin_bit_cast(unsigned int, f);
  u += 0x7fffu + ((u >> 16) & 1u);          // round-to-nearest-even
  return (u16)(u >> 16);
}

#define AS1(p) ((const __attribute__((address_space(1))) void*)(p))
#define AS3(p) ((__attribute__((address_space(3))) void*)(p))

// ---- GEMM core: verified m97 structure, BK=32 ONLY (R5: BK=64 regressed).
// GEMM_PROLOGUE_AT takes explicit tile origins so callers can swizzle the
// block->tile mapping (XCD locality) without touching the core.
// Two MFMA orders:
//   KSTEP      : acc[mi][ni] = mfma(af[mi], bfv[ni])  -> thread's 4 regs are
//                4 ROWS (quad*4+r), col=lane&15  (m89 layout)
//   KSTEP_SWAP : acc[mi][ni] = mfma(bfv[ni], af[mi])  -> transposed: 4 regs
//                are 4 consecutive COLS (quad*4+r), row=lane&15
//                -> vectorized ushort4/float4 epilogue stores.
#define GEMM_PROLOGUE_AT(bmv, bnv)                                           \
  __shared__ u16 As[128 * 32];                                               \
  __shared__ u16 Bs[128 * 32];                                               \
  const int tid  = threadIdx.x;                                              \
  const int wave = tid >> 6, lane = tid & 63;                                \
  const int wm = (wave >> 1) * 64, wn = (wave & 1) * 64;                     \
  const long bm = (bmv), bn = (bnv);                                         \
  floatx4 acc[4][4] = {};                                                    \
  const int srow = lane >> 2;                                                \
  const int scol = (lane & 3) * 8;                                           \
  const int c0 = wave * 2, c1 = c0 + 1;                                      \
  const int fr = lane & 15;                                                  \
  const int kq = (lane >> 4) * 8;                                            \
  const int oc = (lane >> 4) * 4;   /* swapped layout: col quad offset */

#define GEMM_PROLOGUE() GEMM_PROLOGUE_AT((long)blockIdx.y * 128, (long)blockIdx.x * 128)

#define GEMM_STAGE(Ab, Bb, K, k0)                                            \
    __syncthreads();                                                         \
    __builtin_amdgcn_global_load_lds(AS1(Ab + (long)(c0*16 + srow)*K + k0 + scol), AS3(As + c0*512), 16, 0, 0); \
    __builtin_amdgcn_global_load_lds(AS1(Ab + (long)(c1*16 + srow)*K + k0 + scol), AS3(As + c1*512), 16, 0, 0); \
    __builtin_amdgcn_global_load_lds(AS1(Bb + (long)(c0*16 + srow)*K + k0 + scol), AS3(Bs + c0*512), 16, 0, 0); \
    __builtin_amdgcn_global_load_lds(AS1(Bb + (long)(c1*16 + srow)*K + k0 + scol), AS3(Bs + c1*512), 16, 0, 0); \
    __syncthreads();                                                         \
    bf16x8 af[4], bfv[4];                                                    \
    _Pragma("unroll")                                                        \
    for (int mi = 0; mi < 4; ++mi)                                           \
      af[mi] = *(const bf16x8*)(As + (wm + mi*16 + fr)*32 + kq);             \
    _Pragma("unroll")                                                        \
    for (int ni = 0; ni < 4; ++ni)                                           \
      bfv[ni] = *(const bf16x8*)(Bs + (wn + ni*16 + fr)*32 + kq);

#define GEMM_KSTEP(Ab, Bb, K, k0)                                            \
  {                                                                          \
    GEMM_STAGE(Ab, Bb, K, k0)                                                \
    _Pragma("unroll")                                                        \
    for (int mi = 0; mi < 4; ++mi)                                           \
      _Pragma("unroll")                                                      \
      for (int ni = 0; ni < 4; ++ni)                                         \
        acc[mi][ni] = __builtin_amdgcn_mfma_f32_16x16x32_bf16(af[mi], bfv[ni], acc[mi][ni], 0, 0, 0); \
  }

#define GEMM_KSTEP_SWAP(Ab, Bb, K, k0)                                       \
  {                                                                          \
    GEMM_STAGE(Ab, Bb, K, k0)                                                \
    _Pragma("unroll")                                                        \
    for (int mi = 0; mi < 4; ++mi)                                           \
      _Pragma("unroll")                                                      \
      for (int ni = 0; ni < 4; ++ni)                                         \
        acc[mi][ni] = __builtin_amdgcn_mfma_f32_16x16x32_bf16(bfv[ni], af[mi], acc[mi][ni], 0, 0, 0); \
  }

// Final projection: C = A*Bt^T + bias, fp32 out, swapped epilogue (float4).
__global__ __launch_bounds__(256) void gemm_bt(
    const u16* __restrict__ A, const u16* __restrict__ Bt,
    float* __restrict__ Cout, const float* __restrict__ bias, int N, int K)
{
  GEMM_PROLOGUE();
  const u16* Ab = A + bm * K;
  const u16* Bb = Bt + bn * K;
  for (int k0 = 0; k0 < K; k0 += 32) GEMM_KSTEP_SWAP(Ab, Bb, K, k0);

#pragma unroll
  for (int mi = 0; mi < 4; ++mi) {
    long row = bm + wm + mi*16 + fr;
#pragma unroll
    for (int ni = 0; ni < 4; ++ni) {
      long colb = bn + wn + ni*16 + oc;
      float4 bv4 = *(const float4*)(bias + colb);
      float4 o;
      o.x = acc[mi][ni][0] + bv4.x;
      o.y = acc[mi][ni][1] + bv4.y;
      o.z = acc[mi][ni][2] + bv4.z;
      o.w = acc[mi][ni][3] + bv4.w;
      *(float4*)(Cout + row * N + colb) = o;
    }
  }
}

// Batch-combined QK^T + unnormalized exp, XCD-swizzled, swapped epilogue.
// Grid (32,32,2) = 2048 blocks. lin%8 = XCD; batch = xcd>>2; each XCD owns an
// 8-row by-band of one batch, sweeps bx in 8-wide tiles (4MB L2 window).
// P[b] = exp(scale*q k^T) bf16 (ushort4 stores); lpartT[b][row][64] fp32.
// No max-subtraction: |scores| <= ~20 << 88 (fp32 exp range).
__global__ __launch_bounds__(256) void gemm_qk_exp(
    const u16* __restrict__ q, const u16* __restrict__ k,
    u16* __restrict__ probs, float* __restrict__ lpartT, float alpha)
{
  const int N = 4096, K = 1024;
  const int lin = blockIdx.x + (blockIdx.y << 5) + (blockIdx.z << 10);
  const int xcd = lin & 7, j = lin >> 3;          // j in [0,256)
  const long b = xcd >> 2;
  const int band = (xcd & 3) * 8;                 // by-band base
  const int t = j >> 6, w = j & 63;               // 4 bx-tiles of 64 blocks
  const int bx = t * 8 + (w & 7);                 // [0,32)
  const int by = band + (w >> 3);                 // [0,32)

  const u16* A  = q + b * 4096 * 1024;
  const u16* Bt = k + b * 4096 * 1024;
  u16* P = probs + b * 4096L * 4096;
  float* lp = lpartT + b * 4096 * 64;

  GEMM_PROLOGUE_AT((long)by * 128, (long)bx * 128);
  const u16* Ab = A + bm * K;
  const u16* Bb = Bt + bn * K;
  for (int k0 = 0; k0 < K; k0 += 32) GEMM_KSTEP_SWAP(Ab, Bb, K, k0);

  // swapped layout: q-row = bm+wm+mi*16+fr; k-cols = bn+wn+ni*16+oc+{0..3}
  float rowsum[4] = {0.f, 0.f, 0.f, 0.f};
#pragma unroll
  for (int mi = 0; mi < 4; ++mi) {
    long row = bm + wm + mi*16 + fr;
#pragma unroll
    for (int ni = 0; ni < 4; ++ni) {
      long colb = bn + wn + ni*16 + oc;
      float e0 = __expf(acc[mi][ni][0] * alpha);
      float e1 = __expf(acc[mi][ni][1] * alpha);
      float e2 = __expf(acc[mi][ni][2] * alpha);
      float e3 = __expf(acc[mi][ni][3] * alpha);
      rowsum[mi] += (e0 + e1) + (e2 + e3);
      ushort4 o;
      o.x = f2bf(e0); o.y = f2bf(e1); o.z = f2bf(e2); o.w = f2bf(e3);
      *(ushort4*)(P + row * N + colb) = o;
    }
  }
  // lanes {l, l^16, l^32, l^48} share fr (same q-row): reduce over quads.
  const long cg = bx * 2 + (wn >> 6);
#pragma unroll
  for (int mi = 0; mi < 4; ++mi) {
    float s = rowsum[mi];
    s += __shfl_xor(s, 16); s += __shfl_xor(s, 32);
    if (lane < 16)
      lp[(bm + wm + mi*16 + lane) * 64 + cg] = s;
  }
}

// Fused QKV projection: A=xb [8192,1024], Bt=WqkvT [3072,1024], grid (24,64).
// Block-uniform region: bn<2048 -> q/k (swapped epilogue, ushort4 stores);
// bn>=2048 -> vT[b][d][s] (original order; transposed store already ushort4).
__global__ __launch_bounds__(256) void gemm_qkv(
    const u16* __restrict__ A, const u16* __restrict__ Bt,
    u16* __restrict__ qb, u16* __restrict__ kb, u16* __restrict__ vT,
    const float* __restrict__ bq, const float* __restrict__ bk,
    const float* __restrict__ bv)
{
  const int K = 1024;
  GEMM_PROLOGUE();
  const u16* Ab = A + bm * K;
  const u16* Bb = Bt + bn * K;

  if (bn < 2048) {
    for (int k0 = 0; k0 < K; k0 += 32) GEMM_KSTEP_SWAP(Ab, Bb, K, k0);
    u16* C = (bn < 1024) ? qb : kb;
    const float* bias = (bn < 1024) ? bq : bk;
#pragma unroll
    for (int mi = 0; mi < 4; ++mi) {
      long row = bm + wm + mi*16 + fr;
#pragma unroll
      for (int ni = 0; ni < 4; ++ni) {
        long colg = bn + wn + ni*16 + oc;
        long cc = colg & 1023;
        float4 bv4 = *(const float4*)(bias + cc);
        ushort4 o;
        o.x = f2bf(acc[mi][ni][0] + bv4.x);
        o.y = f2bf(acc[mi][ni][1] + bv4.y);
        o.z = f2bf(acc[mi][ni][2] + bv4.z);
        o.w = f2bf(acc[mi][ni][3] + bv4.w);
        *(ushort4*)(C + row * 1024 + cc) = o;
      }
    }
  } else {
    for (int k0 = 0; k0 < K; k0 += 32) GEMM_KSTEP(Ab, Bb, K, k0);
    const int orow = (lane >> 4) * 4;
    const int ocol = lane & 15;
#pragma unroll
    for (int ni = 0; ni < 4; ++ni) {
      long col = bn + wn + ni*16 + ocol;
      float bvv = bv[col - 2048];
#pragma unroll
      for (int mi = 0; mi < 4; ++mi) {
        long row = bm + wm + mi*16 + orow;
        long b_ = row >> 12, s = row & 4095, d = col - 2048;
        ushort4 o;
        o.x = f2bf(acc[mi][ni][0] + bvv);
        o.y = f2bf(acc[mi][ni][1] + bvv);
        o.z = f2bf(acc[mi][ni][2] + bvv);
        o.w = f2bf(acc[mi][ni][3] + bvv);
        *(ushort4*)(vT + b_ * (1024L * 4096) + d * 4096L + s) = o;
      }
    }
  }
}

// Batch-combined PV split-K=2, XCD-swizzled, swapped epilogue (float4, full
// 64B segments). Grid (8,32,4) = 1024 blocks; each (batch,split) K-slice is
// owned by one XCD pair (R7 fixed the 277MB cross-XCD refetch).
__global__ __launch_bounds__(256) void gemm_pv_splitk(
    const u16* __restrict__ probs, const u16* __restrict__ vT,
    float* __restrict__ pA, float* __restrict__ pB)
{
  const int N = 1024, K = 4096, Ks = 2048;
  const int lin = blockIdx.x + (blockIdx.y << 3) + (blockIdx.z << 8);
  const int xcd = lin & 7, j = lin >> 3;          // j in [0,128)
  const int slice = xcd >> 1, half = xcd & 1;
  const long b = slice >> 1;
  const int sp = slice & 1;
  const int bx = j & 7;                           // [0,8)
  const int by = (j >> 3) * 2 + half;             // [0,32)

  const u16* A  = probs + b * 4096L * 4096;
  const u16* Bt = vT + b * 1024L * 4096;
  float* part = (b ? pB : pA) + sp * 4096L * 1024;

  GEMM_PROLOGUE_AT((long)by * 128, (long)bx * 128);
  const u16* Ab = A + bm * K;
  const u16* Bb = Bt + bn * K;
  const int kbeg = sp * Ks, kend = kbeg + Ks;
  for (int k0 = kbeg; k0 < kend; k0 += 32) GEMM_KSTEP_SWAP(Ab, Bb, K, k0);

#pragma unroll
  for (int mi = 0; mi < 4; ++mi) {
    long row = bm + wm + mi*16 + fr;
#pragma unroll
    for (int ni = 0; ni < 4; ++ni) {
      long colb = bn + wn + ni*16 + oc;
      float4 o;
      o.x = acc[mi][ni][0]; o.y = acc[mi][ni][1];
      o.z = acc[mi][ni][2]; o.w = acc[mi][ni][3];
      *(float4*)(part + row * N + colb) = o;
    }
  }
}

// Combined reduce + softmax-normalize: grid (4096 rows, 2 batches).
// Wave 0 reads the row's 64 lpartT entries (coalesced 256B), shuffle-sums,
// broadcasts; out[b][row] = (slice0 + slice1) / l as bf16.
__global__ __launch_bounds__(256) void reduce2_div_row(
    const float* __restrict__ pA, const float* __restrict__ pB,
    const float* __restrict__ lpartT, u16* __restrict__ ob)
{
  const int row = blockIdx.x;           // [0,4096)
  const long b = blockIdx.y;
  const int tid = threadIdx.x;
  const float* part = b ? pB : pA;
  const float* lp = lpartT + b * 4096 * 64;
  __shared__ float sl;
  if (tid < 64) {
    float s = lp[(long)row * 64 + tid];
#pragma unroll
    for (int off = 32; off; off >>= 1) s += __shfl_down(s, off);
    if (tid == 0) sl = s;
  }
  __syncthreads();
  const float inv = 1.0f / sl;
  const long base = (long)row * 1024 + tid * 4;
  float4 a  = *(const float4*)(part + base);
  float4 b2 = *(const float4*)(part + 4096L * 1024 + base);
  ushort4 o;
  o.x = f2bf((a.x + b2.x) * inv);
  o.y = f2bf((a.y + b2.y) * inv);
  o.z = f2bf((a.z + b2.z) * inv);
  o.w = f2bf((a.w + b2.w) * inv);
  *(ushort4*)(ob + b * 4096L * 1024 + base) = o;
}

__global__ __launch_bounds__(256) void cast_f32_to_bf16(
    const float* __restrict__ in, u16* __restrict__ out, int n4)
{
  int i = blockIdx.x * 256 + threadIdx.x;
  if (i >= n4) return;
  float4 f = ((const float4*)in)[i];
  ushort4 o;
  o.x = f2bf(f.x); o.y = f2bf(f.y); o.z = f2bf(f.z); o.w = f2bf(f.w);
  ((ushort4*)out)[i] = o;
}

// z in [0,4): out_z[c][r] = (bf16)in_z[r][c], 1024x1024 each
__global__ void transpose_w4(
    const float* __restrict__ W0, const float* __restrict__ W1,
    const float* __restrict__ W2, const float* __restrict__ W3,
    u16* __restrict__ O0, u16* __restrict__ O1,
    u16* __restrict__ O2, u16* __restrict__ O3)
{
  __shared__ float tile[32][33];
  const int z = blockIdx.z;
  const float* in = (z == 0) ? W0 : (z == 1) ? W1 : (z == 2) ? W2 : W3;
  u16* out = (z == 0) ? O0 : (z == 1) ? O1 : (z == 2) ? O2 : O3;
  int bx = blockIdx.x * 32, by = blockIdx.y * 32;
  int tx = threadIdx.x, ty = threadIdx.y;
  for (int i = ty; i < 32; i += 8)
    tile[i][tx] = in[(long)(by + i) * 1024 + bx + tx];
  __syncthreads();
  for (int i = ty; i < 32; i += 8)
    out[(long)(bx + i) * 1024 + by + tx] = f2bf(tile[tx][i]);
}

extern "C" void kernel_launch(void* const* d_in, const int* in_sizes, int n_in,
                              void* d_out, int out_size, void* d_ws, size_t ws_size,
                              hipStream_t stream) {
  const float* x  = (const float*)d_in[0];
  const float* Wq = (const float*)d_in[1];
  const float* bq = (const float*)d_in[2];
  const float* Wk = (const float*)d_in[3];
  const float* bk = (const float*)d_in[4];
  const float* Wv = (const float*)d_in[5];
  const float* bv = (const float*)d_in[6];
  const float* Wo = (const float*)d_in[7];
  const float* bo = (const float*)d_in[8];
  float* out = (float*)d_out;

  const int B = 2, S = 4096, D = 1024;
  const long MS = (long)B * S;  // 8192
  const long MB = 1L << 20;

  // ---- workspace layout (top usage 168 MiB; ws_size >= 168 MiB proven) ----
  //  [0,16M)    qb  bf16 [8192,1024]   -- dead after QK_exp; reused as
  //  [16,32M)   kb  bf16 [8192,1024]   -- PV partials region A (32M fp32)
  //  [32,48M)   vT  bf16 [B][1024][4096]
  //  [48,64M)   xb  bf16 [8192,1024]   -- aliased with ob (xb dead before PV)
  //  [64,72M)   WqkvT bf16 [3072,1024] + WoT bf16 [1024,1024]
  //  [72,136M)  probs bf16 [B][4096][4096]  (both batches)
  //  [136,168M) PV partials region B (batch 1): [2][4096][1024] fp32
  // d_out (32MB fp32, dead until final proj) hosts lpartT [B][4096][64] fp32.
  char* w = (char*)d_ws;
  u16* qb  = (u16*)(w);
  u16* kb  = (u16*)(w + 16 * MB);
  u16* vT  = (u16*)(w + 32 * MB);
  u16* xb  = (u16*)(w + 48 * MB);
  u16* ob  = xb;                        // alias: xb dead before ob written
  u16* WqkvT = (u16*)(w + 64 * MB);
  u16* WoT = WqkvT + 3072L * 1024;
  u16* probs = (u16*)(w + 72 * MB);
  float* partA = (float*)(w);           // over qb+kb, dead after QK_exp
  float* partB = (float*)(w + 136 * MB);
  float* lpartT = (float*)d_out;        // [2][4096][64] fp32 = 2MB

  // 1. cast x -> bf16
  cast_f32_to_bf16<<<dim3((unsigned)(MS * D / 4 / 256)), dim3(256), 0, stream>>>(
      x, xb, (int)(MS * D / 4));

  // 2. transpose+cast all 4 weights in one launch
  transpose_w4<<<dim3(32, 32, 4), dim3(32, 8), 0, stream>>>(
      Wq, Wk, Wv, Wo, WqkvT, WqkvT + 1024L * 1024, WqkvT + 2048L * 1024, WoT);

  // 3. fused QKV projection: grid (24,64) = 1536 blocks
  gemm_qkv<<<dim3(3 * D / 128, MS / 128), 256, 0, stream>>>(
      xb, WqkvT, qb, kb, vT, bq, bk, bv);

  // 4. attention, both batches per launch (XCD-swizzled kernels)
  const float scale = 0.125f;  // 1/sqrt(64)
  gemm_qk_exp<<<dim3(S / 128, S / 128, B), 256, 0, stream>>>(
      qb, kb, probs, lpartT, scale);
  // qb/kb now dead -> partA overlays them
  gemm_pv_splitk<<<dim3(D / 128, S / 128, 2 * B), 256, 0, stream>>>(
      probs, vT, partA, partB);
  reduce2_div_row<<<dim3(S, B), 256, 0, stream>>>(partA, partB, lpartT, ob);

  // 5. final projection -> fp32 d_out (overwrites lpartT scratch)
  gemm_bt<<<dim3(D / 128, MS / 128), 256, 0, stream>>>(ob, WoT, out, bo, D, D);
}

// Round 9
// 409.180 us; speedup vs baseline: 1.1056x; 1.0439x over previous
//
#include <hip/hip_runtime.h>

// bf16 stored as raw ushort everywhere; MFMA consumes __bf16 vectors.
typedef unsigned short u16;
using bf16x8  = __attribute__((ext_vector_type(8))) __bf16;
using floatx4 = __attribute__((ext_vector_type(4))) float;

__device__ __forceinline__ u16 f2bf(float f) {
  unsigned int u = __builtin_bit_cast(unsigned int, f);
  u += 0x7fffu + ((u >> 16) & 1u);          // round-to-nearest-even
  return (u16)(u >> 16);
}
__device__ __forceinline__ float bf2f(u16 h) {
  unsigned int u = ((unsigned int)h) << 16;
  return __builtin_bit_cast(float, u);
}

#define AS1(p) ((const __attribute__((address_space(1))) void*)(p))
#define AS3(p) ((__attribute__((address_space(3))) void*)(p))

// ---- GEMM core: verified m97 structure, BK=32 ONLY (R5: BK=64 regressed).
// KSTEP      : acc = mfma(af, bfv) -> thread's 4 regs = 4 ROWS (m89 layout)
// KSTEP_SWAP : acc = mfma(bfv, af) -> transposed: 4 regs = 4 consecutive COLS
//              (row = lane&15) -> vectorized ushort4/float4 epilogue stores
//              (R8-verified).
#define GEMM_PROLOGUE_AT(bmv, bnv)                                           \
  __shared__ u16 As[128 * 32];                                               \
  __shared__ u16 Bs[128 * 32];                                               \
  const int tid  = threadIdx.x;                                              \
  const int wave = tid >> 6, lane = tid & 63;                                \
  const int wm = (wave >> 1) * 64, wn = (wave & 1) * 64;                     \
  const long bm = (bmv), bn = (bnv);                                         \
  floatx4 acc[4][4] = {};                                                    \
  const int srow = lane >> 2;                                                \
  const int scol = (lane & 3) * 8;                                           \
  const int c0 = wave * 2, c1 = c0 + 1;                                      \
  const int fr = lane & 15;                                                  \
  const int kq = (lane >> 4) * 8;                                            \
  const int oc = (lane >> 4) * 4;   /* swapped layout: col quad offset */

#define GEMM_PROLOGUE() GEMM_PROLOGUE_AT((long)blockIdx.y * 128, (long)blockIdx.x * 128)

#define GEMM_STAGE(Ab, Bb, K, k0)                                            \
    __syncthreads();                                                         \
    __builtin_amdgcn_global_load_lds(AS1(Ab + (long)(c0*16 + srow)*K + k0 + scol), AS3(As + c0*512), 16, 0, 0); \
    __builtin_amdgcn_global_load_lds(AS1(Ab + (long)(c1*16 + srow)*K + k0 + scol), AS3(As + c1*512), 16, 0, 0); \
    __builtin_amdgcn_global_load_lds(AS1(Bb + (long)(c0*16 + srow)*K + k0 + scol), AS3(Bs + c0*512), 16, 0, 0); \
    __builtin_amdgcn_global_load_lds(AS1(Bb + (long)(c1*16 + srow)*K + k0 + scol), AS3(Bs + c1*512), 16, 0, 0); \
    __syncthreads();                                                         \
    bf16x8 af[4], bfv[4];                                                    \
    _Pragma("unroll")                                                        \
    for (int mi = 0; mi < 4; ++mi)                                           \
      af[mi] = *(const bf16x8*)(As + (wm + mi*16 + fr)*32 + kq);             \
    _Pragma("unroll")                                                        \
    for (int ni = 0; ni < 4; ++ni)                                           \
      bfv[ni] = *(const bf16x8*)(Bs + (wn + ni*16 + fr)*32 + kq);

#define GEMM_KSTEP(Ab, Bb, K, k0)                                            \
  {                                                                          \
    GEMM_STAGE(Ab, Bb, K, k0)                                                \
    _Pragma("unroll")                                                        \
    for (int mi = 0; mi < 4; ++mi)                                           \
      _Pragma("unroll")                                                      \
      for (int ni = 0; ni < 4; ++ni)                                         \
        acc[mi][ni] = __builtin_amdgcn_mfma_f32_16x16x32_bf16(af[mi], bfv[ni], acc[mi][ni], 0, 0, 0); \
  }

#define GEMM_KSTEP_SWAP(Ab, Bb, K, k0)                                       \
  {                                                                          \
    GEMM_STAGE(Ab, Bb, K, k0)                                                \
    _Pragma("unroll")                                                        \
    for (int mi = 0; mi < 4; ++mi)                                           \
      _Pragma("unroll")                                                      \
      for (int ni = 0; ni < 4; ++ni)                                         \
        acc[mi][ni] = __builtin_amdgcn_mfma_f32_16x16x32_bf16(bfv[ni], af[mi], acc[mi][ni], 0, 0, 0); \
  }

// Final projection: C = A*Bt^T + bias, fp32 out, swapped epilogue (float4).
__global__ __launch_bounds__(256) void gemm_bt(
    const u16* __restrict__ A, const u16* __restrict__ Bt,
    float* __restrict__ Cout, const float* __restrict__ bias, int N, int K)
{
  GEMM_PROLOGUE();
  const u16* Ab = A + bm * K;
  const u16* Bb = Bt + bn * K;
  for (int k0 = 0; k0 < K; k0 += 32) GEMM_KSTEP_SWAP(Ab, Bb, K, k0);

#pragma unroll
  for (int mi = 0; mi < 4; ++mi) {
    long row = bm + wm + mi*16 + fr;
#pragma unroll
    for (int ni = 0; ni < 4; ++ni) {
      long colb = bn + wn + ni*16 + oc;
      float4 bv4 = *(const float4*)(bias + colb);
      float4 o;
      o.x = acc[mi][ni][0] + bv4.x;
      o.y = acc[mi][ni][1] + bv4.y;
      o.z = acc[mi][ni][2] + bv4.z;
      o.w = acc[mi][ni][3] + bv4.w;
      *(float4*)(Cout + row * N + colb) = o;
    }
  }
}

// Batch-combined QK^T + unnormalized exp, XCD-swizzled, swapped epilogue.
// Grid (32,32,2) = 2048 blocks. lin%8 = XCD; batch = xcd>>2; each XCD owns an
// 8-row by-band of one batch, sweeps bx in 8-wide tiles (4MB L2 window).
// P[b] = exp(scale*q k^T) bf16 (ushort4 stores); lpartT[b][row][64] fp32.
// No max-subtraction: |scores| <= ~20 << 88 (fp32 exp range).
__global__ __launch_bounds__(256) void gemm_qk_exp(
    const u16* __restrict__ q, const u16* __restrict__ k,
    u16* __restrict__ probs, float* __restrict__ lpartT, float alpha)
{
  const int N = 4096, K = 1024;
  const int lin = blockIdx.x + (blockIdx.y << 5) + (blockIdx.z << 10);
  const int xcd = lin & 7, j = lin >> 3;          // j in [0,256)
  const long b = xcd >> 2;
  const int band = (xcd & 3) * 8;                 // by-band base
  const int t = j >> 6, w = j & 63;               // 4 bx-tiles of 64 blocks
  const int bx = t * 8 + (w & 7);                 // [0,32)
  const int by = band + (w >> 3);                 // [0,32)

  const u16* A  = q + b * 4096 * 1024;
  const u16* Bt = k + b * 4096 * 1024;
  u16* P = probs + b * 4096L * 4096;
  float* lp = lpartT + b * 4096 * 64;

  GEMM_PROLOGUE_AT((long)by * 128, (long)bx * 128);
  const u16* Ab = A + bm * K;
  const u16* Bb = Bt + bn * K;
  for (int k0 = 0; k0 < K; k0 += 32) GEMM_KSTEP_SWAP(Ab, Bb, K, k0);

  // swapped layout: q-row = bm+wm+mi*16+fr; k-cols = bn+wn+ni*16+oc+{0..3}
  float rowsum[4] = {0.f, 0.f, 0.f, 0.f};
#pragma unroll
  for (int mi = 0; mi < 4; ++mi) {
    long row = bm + wm + mi*16 + fr;
#pragma unroll
    for (int ni = 0; ni < 4; ++ni) {
      long colb = bn + wn + ni*16 + oc;
      float e0 = __expf(acc[mi][ni][0] * alpha);
      float e1 = __expf(acc[mi][ni][1] * alpha);
      float e2 = __expf(acc[mi][ni][2] * alpha);
      float e3 = __expf(acc[mi][ni][3] * alpha);
      rowsum[mi] += (e0 + e1) + (e2 + e3);
      ushort4 o;
      o.x = f2bf(e0); o.y = f2bf(e1); o.z = f2bf(e2); o.w = f2bf(e3);
      *(ushort4*)(P + row * N + colb) = o;
    }
  }
  // lanes {l, l^16, l^32, l^48} share fr (same q-row): reduce over quads.
  const long cg = bx * 2 + (wn >> 6);
#pragma unroll
  for (int mi = 0; mi < 4; ++mi) {
    float s = rowsum[mi];
    s += __shfl_xor(s, 16); s += __shfl_xor(s, 32);
    if (lane < 16)
      lp[(bm + wm + mi*16 + lane) * 64 + cg] = s;
  }
}

// Fused QKV projection: A=xb [8192,1024], Bt=WqkvT [3072,1024], grid (24,64).
// Block-uniform region: bn<2048 -> q/k (swapped epilogue, ushort4 stores);
// bn>=2048 -> vT[b][d][s] (original order; transposed store already ushort4).
__global__ __launch_bounds__(256) void gemm_qkv(
    const u16* __restrict__ A, const u16* __restrict__ Bt,
    u16* __restrict__ qb, u16* __restrict__ kb, u16* __restrict__ vT,
    const float* __restrict__ bq, const float* __restrict__ bk,
    const float* __restrict__ bv)
{
  const int K = 1024;
  GEMM_PROLOGUE();
  const u16* Ab = A + bm * K;
  const u16* Bb = Bt + bn * K;

  if (bn < 2048) {
    for (int k0 = 0; k0 < K; k0 += 32) GEMM_KSTEP_SWAP(Ab, Bb, K, k0);
    u16* C = (bn < 1024) ? qb : kb;
    const float* bias = (bn < 1024) ? bq : bk;
#pragma unroll
    for (int mi = 0; mi < 4; ++mi) {
      long row = bm + wm + mi*16 + fr;
#pragma unroll
      for (int ni = 0; ni < 4; ++ni) {
        long colg = bn + wn + ni*16 + oc;
        long cc = colg & 1023;
        float4 bv4 = *(const float4*)(bias + cc);
        ushort4 o;
        o.x = f2bf(acc[mi][ni][0] + bv4.x);
        o.y = f2bf(acc[mi][ni][1] + bv4.y);
        o.z = f2bf(acc[mi][ni][2] + bv4.z);
        o.w = f2bf(acc[mi][ni][3] + bv4.w);
        *(ushort4*)(C + row * 1024 + cc) = o;
      }
    }
  } else {
    for (int k0 = 0; k0 < K; k0 += 32) GEMM_KSTEP(Ab, Bb, K, k0);
    const int orow = (lane >> 4) * 4;
    const int ocol = lane & 15;
#pragma unroll
    for (int ni = 0; ni < 4; ++ni) {
      long col = bn + wn + ni*16 + ocol;
      float bvv = bv[col - 2048];
#pragma unroll
      for (int mi = 0; mi < 4; ++mi) {
        long row = bm + wm + mi*16 + orow;
        long b_ = row >> 12, s = row & 4095, d = col - 2048;
        ushort4 o;
        o.x = f2bf(acc[mi][ni][0] + bvv);
        o.y = f2bf(acc[mi][ni][1] + bvv);
        o.z = f2bf(acc[mi][ni][2] + bvv);
        o.w = f2bf(acc[mi][ni][3] + bvv);
        *(ushort4*)(vT + b_ * (1024L * 4096) + d * 4096L + s) = o;
      }
    }
  }
}

// Batch-combined PV split-K=4, bf16 partials, perfect XCD mapping:
// xcd = blockIdx.x = batch*4 + K-quarter. Each XCD streams exactly one
// 8MB probs K-slice + 2MB vT slice once. Grid (8,32,8) = 2048 blocks = 8/CU.
// Swapped epilogue -> ushort4 partial stores (half the R8 write traffic).
__global__ __launch_bounds__(256) void gemm_pv_splitk(
    const u16* __restrict__ probs, const u16* __restrict__ vT,
    u16* __restrict__ pA, u16* __restrict__ pB)
{
  const int N = 1024, K = 4096, Ks = 1024;
  const int lin = blockIdx.x + (blockIdx.y << 3) + (blockIdx.z << 8);
  const int xcd = lin & 7, j = lin >> 3;          // j in [0,256)
  const long b = xcd >> 2;
  const int sp = xcd & 3;                         // K-quarter
  const int bx = j & 7;                           // [0,8)
  const int by = j >> 3;                          // [0,32)

  const u16* A  = probs + b * 4096L * 4096;
  const u16* Bt = vT + b * 1024L * 4096;
  u16* part = (b ? pB : pA) + (long)sp * 4096 * 1024;

  GEMM_PROLOGUE_AT((long)by * 128, (long)bx * 128);
  const u16* Ab = A + bm * K;
  const u16* Bb = Bt + bn * K;
  const int kbeg = sp * Ks, kend = kbeg + Ks;
  for (int k0 = kbeg; k0 < kend; k0 += 32) GEMM_KSTEP_SWAP(Ab, Bb, K, k0);

#pragma unroll
  for (int mi = 0; mi < 4; ++mi) {
    long row = bm + wm + mi*16 + fr;
#pragma unroll
    for (int ni = 0; ni < 4; ++ni) {
      long colb = bn + wn + ni*16 + oc;
      ushort4 o;
      o.x = f2bf(acc[mi][ni][0]);
      o.y = f2bf(acc[mi][ni][1]);
      o.z = f2bf(acc[mi][ni][2]);
      o.w = f2bf(acc[mi][ni][3]);
      *(ushort4*)(part + row * N + colb) = o;
    }
  }
}

// Combined reduce + softmax-normalize: grid (4096 rows, 2 batches).
// Wave 0 reads the row's 64 lpartT entries (coalesced 256B), shuffle-sums,
// broadcasts; out[b][row] = (s0+s1+s2+s3)/l as bf16 (partials are bf16).
__global__ __launch_bounds__(256) void reduce4_div_row(
    const u16* __restrict__ pA, const u16* __restrict__ pB,
    const float* __restrict__ lpartT, u16* __restrict__ ob)
{
  const int row = blockIdx.x;           // [0,4096)
  const long b = blockIdx.y;
  const int tid = threadIdx.x;
  const u16* part = b ? pB : pA;
  const float* lp = lpartT + b * 4096 * 64;
  __shared__ float sl;
  if (tid < 64) {
    float s = lp[(long)row * 64 + tid];
#pragma unroll
    for (int off = 32; off; off >>= 1) s += __shfl_down(s, off);
    if (tid == 0) sl = s;
  }
  __syncthreads();
  const float inv = 1.0f / sl;
  const long base = (long)row * 1024 + tid * 4;
  float acc4[4] = {0.f, 0.f, 0.f, 0.f};
#pragma unroll
  for (int s = 0; s < 4; ++s) {
    ushort4 p = *(const ushort4*)(part + (long)s * 4096 * 1024 + base);
    acc4[0] += bf2f(p.x); acc4[1] += bf2f(p.y);
    acc4[2] += bf2f(p.z); acc4[3] += bf2f(p.w);
  }
  ushort4 o;
  o.x = f2bf(acc4[0] * inv);
  o.y = f2bf(acc4[1] * inv);
  o.z = f2bf(acc4[2] * inv);
  o.w = f2bf(acc4[3] * inv);
  *(ushort4*)(ob + b * 4096L * 1024 + base) = o;
}

// Fused prep: blocks [0,8192) cast x (fp32->bf16, float4); blocks
// [8192,12288) transpose+cast the 4 weight matrices (z = (blk-8192)>>10).
__global__ __launch_bounds__(256) void prep(
    const float* __restrict__ x, u16* __restrict__ xb,
    const float* __restrict__ W0, const float* __restrict__ W1,
    const float* __restrict__ W2, const float* __restrict__ W3,
    u16* __restrict__ O0, u16* __restrict__ O1,
    u16* __restrict__ O2, u16* __restrict__ O3)
{
  __shared__ float tile[32][33];
  int blk = blockIdx.x;
  if (blk < 8192) {
    int i = blk * 256 + threadIdx.x;      // 2M float4s
    float4 f = ((const float4*)x)[i];
    ushort4 o;
    o.x = f2bf(f.x); o.y = f2bf(f.y); o.z = f2bf(f.z); o.w = f2bf(f.w);
    ((ushort4*)xb)[i] = o;
  } else {
    blk -= 8192;
    const int z = blk >> 10, t = blk & 1023;
    const float* in = (z == 0) ? W0 : (z == 1) ? W1 : (z == 2) ? W2 : W3;
    u16* outp = (z == 0) ? O0 : (z == 1) ? O1 : (z == 2) ? O2 : O3;
    const int bx = (t & 31) * 32, by = (t >> 5) * 32;
    const int tx = threadIdx.x & 31, ty = threadIdx.x >> 5;   // 32 x 8
    for (int i = ty; i < 32; i += 8)
      tile[i][tx] = in[(long)(by + i) * 1024 + bx + tx];
    __syncthreads();
    for (int i = ty; i < 32; i += 8)
      outp[(long)(bx + i) * 1024 + by + tx] = f2bf(tile[tx][i]);
  }
}

extern "C" void kernel_launch(void* const* d_in, const int* in_sizes, int n_in,
                              void* d_out, int out_size, void* d_ws, size_t ws_size,
                              hipStream_t stream) {
  const float* x  = (const float*)d_in[0];
  const float* Wq = (const float*)d_in[1];
  const float* bq = (const float*)d_in[2];
  const float* Wk = (const float*)d_in[3];
  const float* bk = (const float*)d_in[4];
  const float* Wv = (const float*)d_in[5];
  const float* bv = (const float*)d_in[6];
  const float* Wo = (const float*)d_in[7];
  const float* bo = (const float*)d_in[8];
  float* out = (float*)d_out;

  const int B = 2, S = 4096, D = 1024;
  const long MS = (long)B * S;  // 8192
  const long MB = 1L << 20;

  // ---- workspace layout (top usage 168 MiB; ws_size >= 168 MiB proven) ----
  //  [0,16M)    qb  bf16 [8192,1024]   -- dead after QK_exp; reused as
  //  [16,32M)   kb  bf16 [8192,1024]   -- PV bf16 partials batch0 [4][4096][1024]
  //  [32,48M)   vT  bf16 [B][1024][4096]
  //  [48,64M)   xb  bf16 [8192,1024]   -- aliased with ob (xb dead before PV)
  //  [64,72M)   WqkvT bf16 [3072,1024] + WoT bf16 [1024,1024]
  //  [72,136M)  probs bf16 [B][4096][4096]  (both batches)
  //  [136,168M) PV bf16 partials batch1 [4][4096][1024] (32M region, 32M used)
  // d_out (32MB fp32, dead until final proj) hosts lpartT [B][4096][64] fp32.
  char* w = (char*)d_ws;
  u16* qb  = (u16*)(w);
  u16* kb  = (u16*)(w + 16 * MB);
  u16* vT  = (u16*)(w + 32 * MB);
  u16* xb  = (u16*)(w + 48 * MB);
  u16* ob  = xb;                        // alias: xb dead before ob written
  u16* WqkvT = (u16*)(w + 64 * MB);
  u16* WoT = WqkvT + 3072L * 1024;
  u16* probs = (u16*)(w + 72 * MB);
  u16* partA = (u16*)(w);               // over qb+kb, dead after QK_exp
  u16* partB = (u16*)(w + 136 * MB);
  float* lpartT = (float*)d_out;        // [2][4096][64] fp32 = 2MB

  // 1. fused prep: cast x + transpose/cast all 4 weights
  prep<<<dim3(8192 + 4096), 256, 0, stream>>>(
      x, xb, Wq, Wk, Wv, Wo,
      WqkvT, WqkvT + 1024L * 1024, WqkvT + 2048L * 1024, WoT);

  // 2. fused QKV projection: grid (24,64) = 1536 blocks
  gemm_qkv<<<dim3(3 * D / 128, MS / 128), 256, 0, stream>>>(
      xb, WqkvT, qb, kb, vT, bq, bk, bv);

  // 3. attention, both batches per launch (XCD-swizzled kernels)
  const float scale = 0.125f;  // 1/sqrt(64)
  gemm_qk_exp<<<dim3(S / 128, S / 128, B), 256, 0, stream>>>(
      qb, kb, probs, lpartT, scale);
  // qb/kb now dead -> partA overlays them
  gemm_pv_splitk<<<dim3(D / 128, S / 128, 8), 256, 0, stream>>>(
      probs, vT, partA, partB);
  reduce4_div_row<<<dim3(S, B), 256, 0, stream>>>(partA, partB, lpartT, ob);

  // 4. final projection -> fp32 d_out (overwrites lpartT scratch)
  gemm_bt<<<dim3(D / 128, MS / 128), 256, 0, stream>>>(ob, WoT, out, bo, D, D);
}